// Round 8
// baseline (309.483 us; speedup 1.0000x reference)
//
#include <hip/hip_runtime.h>
#include <stdint.h>

// OctonionLinear == GEMM: out[b, i*8+k] = sum_{j,p} x[b, j*8+p] * W[i,j,p,k] + bias[i,k]
// M=512, N=4096, K=4096, fp32 in/out, bf16 MFMA.
// R8: fused last-block reduction. Cross-round accounting shows dur_us =
//   ~65us fixed harness resets (256MiB ws poison + d_in restore, measured via
//   fillBufferAligned dispatches) + prep ~35 + gemm ~32 + reduce ~7. This
//   round removes the reduce kernel: all KSPLIT=4 blocks store fp32 partials
//   (plain stores, R7), then a per-tile device-scope arrival counter elects
//   the last block, which sums the 4 slices in fixed z-order (deterministic),
//   adds bias, writes out. GEMM main loop identical to R7 (512 thr, 128x128
//   tile, 8 waves of 64x32, dbuf global_load_lds staging).

#define M_DIM 512
#define N_DIM 4096
#define K_DIM 4096
#define KSPLIT 4
#define NIT ((K_DIM / KSPLIT) / 32)            // 32
#define PART_ELEMS (M_DIM * N_DIM)             // 2097152 floats per z-slice
#define N_TILES ((N_DIM / 128) * (M_DIM / 128))  // 128 tiles

typedef __bf16 bf16x8 __attribute__((ext_vector_type(8)));
typedef float f32x4 __attribute__((ext_vector_type(4)));

__device__ inline unsigned short f2bf(float f) {
  union { float f; unsigned int u; } v;
  v.f = f;
  unsigned int u = v.u;
  unsigned int r = (u + 0x7fffu + ((u >> 16) & 1u)) >> 16;  // RNE
  return (unsigned short)r;
}

// blocks [0,4096): W transpose+convert -> bt[nn][kk], coalesced 16KB chunks.
// blocks [4096,5120): x convert -> abf, 8 el/thread; bid==4096 zeroes cnt.
// blocks [5120,7168): out = bias broadcast (ONLY in atomic fallback path).
__global__ __launch_bounds__(256) void prep_kernel(
    const float* __restrict__ x, const float* __restrict__ w,
    const float* __restrict__ bias, unsigned short* __restrict__ abf,
    unsigned short* __restrict__ bt, float* __restrict__ out,
    int* __restrict__ cnt) {
  const int bid = blockIdx.x;
  const int t = threadIdx.x;
  if (bid < 4096) {
    __shared__ __align__(16) unsigned short lT[8][512];  // [k][j'*8+p], 8KB
    const int i = bid >> 3;
    const int jg = bid & 7;
    const float4* src =
        (const float4*)(w + (size_t)i * 32768 + jg * 4096 + t * 16);
    float4 v0 = src[0], v1 = src[1], v2 = src[2], v3 = src[3];
    const int jp = (t >> 2) * 8 + (t & 3) * 2;  // j'*8 + p0 (even)
    const float* lo = (const float*)&v0;  // k=0..3, p0   (v1: k=4..7)
    const float* hi = (const float*)&v2;  // k=0..3, p0+1 (v3: k=4..7)
#pragma unroll
    for (int k = 0; k < 4; ++k) {
      unsigned int pk =
          (unsigned int)f2bf(lo[k]) | ((unsigned int)f2bf(hi[k]) << 16);
      *(unsigned int*)&lT[k][jp] = pk;
    }
    lo = (const float*)&v1;
    hi = (const float*)&v3;
#pragma unroll
    for (int k = 0; k < 4; ++k) {
      unsigned int pk =
          (unsigned int)f2bf(lo[k]) | ((unsigned int)f2bf(hi[k]) << 16);
      *(unsigned int*)&lT[k + 4][jp] = pk;
    }
    __syncthreads();
    const int r = t >> 5, c = t & 31;  // 32B/thread, 1KB contiguous runs
    const uint4* s = (const uint4*)&lT[r][c * 16];
    uint4* d = (uint4*)(bt + (size_t)(i * 8 + r) * K_DIM + jg * 512 + c * 16);
    d[0] = s[0];
    d[1] = s[1];
  } else if (bid < 5120) {
    if (bid == 4096 && t < N_TILES) cnt[t] = 0;  // ws is 0xAA-poisoned
    int g = (bid - 4096) * 256 + t;  // [0, 262144); 8 elements each
    const float4* xi = (const float4*)x;
    float4 a = xi[g * 2];
    float4 b = xi[g * 2 + 1];
    __attribute__((aligned(16))) unsigned short o[8] = {
        f2bf(a.x), f2bf(a.y), f2bf(a.z), f2bf(a.w),
        f2bf(b.x), f2bf(b.y), f2bf(b.z), f2bf(b.w)};
    *(uint4*)(abf + (size_t)g * 8) = *(const uint4*)o;
  } else {
    int g = (bid - 5120) * 256 + t;  // [0, 524288); 4 elements each
    int el = g * 4;
    int col = el & (N_DIM - 1);
    *(float4*)(out + el) = *(const float4*)(bias + col);
  }
}

__device__ inline void gld16(const void* g, void* l) {
  __builtin_amdgcn_global_load_lds(
      (const __attribute__((address_space(1))) unsigned int*)g,
      (__attribute__((address_space(3))) unsigned int*)l, 16, 0, 0);
}

// Tile 128M x 128N, BK=32, 512 threads = 8 waves, wave-tile 64M x 32N (4x2).
// LDS: A 128x32 (8KB) + B 128x32 (8KB) per buffer, dbuf = 32KB.
__global__ __launch_bounds__(512, 4) void gemm_kernel(
    const unsigned short* __restrict__ A, const unsigned short* __restrict__ Bt,
    const float* __restrict__ bias, float* __restrict__ out,
    float* __restrict__ part, int* __restrict__ cnt, int use_atomic) {
  __shared__ __align__(16) char lds[2][16 * 1024];
  const int t = threadIdx.x;
  const int n0 = blockIdx.x * 128;
  const int m0 = blockIdx.y * 128;
  const int z = blockIdx.z;
  const int kc0 = z * (K_DIM / KSPLIT);
  const int w = t >> 6;
  const int lane = t & 63;
  const int wr = w >> 2;     // 0..1 -> 64 M-rows
  const int wc = w & 3;      // 0..3 -> 32 N-cols
  const int lrow = lane & 15;
  const int kb = lane >> 4;  // k-block 0..3 (8 bf16 each)

  f32x4 acc[4][2] = {};

  // staging: each thread 1 A-seg + 1 B-seg of 16B: row t>>2, col (t&3)*8.
  // LDS dest = wave-uniform base (w*1024) + lane*16 == lds + t*16.
  const size_t aOff = (size_t)(m0 + (t >> 2)) * K_DIM + kc0 + (t & 3) * 8;
  const size_t bOff = (size_t)(n0 + (t >> 2)) * K_DIM + kc0 + (t & 3) * 8;

  auto issue = [&](int it) {
    char* buf = lds[it & 1];
    gld16(A + aOff + it * 32, buf + t * 16);
    gld16(Bt + bOff + it * 32, buf + 8192 + t * 16);
  };

  issue(0);
  for (int it = 0; it < NIT; ++it) {
    __syncthreads();
    if (it + 1 < NIT) issue(it + 1);
    const unsigned short* cA = (const unsigned short*)lds[it & 1];
    const unsigned short* cB = cA + 4096;  // +8KB

    bf16x8 af[4], bfr[2];
#pragma unroll
    for (int mt = 0; mt < 4; ++mt)
      af[mt] = *(const bf16x8*)(cA + (wr * 64 + mt * 16 + lrow) * 32 + kb * 8);
#pragma unroll
    for (int nt = 0; nt < 2; ++nt)
      bfr[nt] = *(const bf16x8*)(cB + (wc * 32 + nt * 16 + lrow) * 32 + kb * 8);
#pragma unroll
    for (int mt = 0; mt < 4; ++mt)
#pragma unroll
      for (int nt = 0; nt < 2; ++nt)
        acc[mt][nt] = __builtin_amdgcn_mfma_f32_16x16x32_bf16(
            af[mt], bfr[nt], acc[mt][nt], 0, 0, 0);
  }

  // C/D layout (verified m89/m91): col = lane&15, row = (lane>>4)*4 + reg
  if (use_atomic) {
#pragma unroll
    for (int mt = 0; mt < 4; ++mt) {
      const int gmb = m0 + wr * 64 + mt * 16 + kb * 4;
#pragma unroll
      for (int nt = 0; nt < 2; ++nt) {
        const int gn = n0 + wc * 32 + nt * 16 + lrow;
#pragma unroll
        for (int r = 0; r < 4; ++r)
          atomicAdd(out + (size_t)(gmb + r) * N_DIM + gn, acc[mt][nt][r]);
      }
    }
    return;
  }

  // --- partial store + last-block fused reduction ---
  float* p = part + (size_t)z * PART_ELEMS;
#pragma unroll
  for (int mt = 0; mt < 4; ++mt) {
    const int gmb = m0 + wr * 64 + mt * 16 + kb * 4;
#pragma unroll
    for (int nt = 0; nt < 2; ++nt) {
      const int gn = n0 + wc * 32 + nt * 16 + lrow;
#pragma unroll
      for (int r = 0; r < 4; ++r)
        p[(size_t)(gmb + r) * N_DIM + gn] = acc[mt][nt][r];
    }
  }
  __threadfence();  // release: partials visible device-wide before count

  __shared__ int lastFlag;
  if (t == 0) {
    const int tile = blockIdx.y * (N_DIM / 128) + blockIdx.x;
    int old = __hip_atomic_fetch_add(&cnt[tile], 1, __ATOMIC_ACQ_REL,
                                     __HIP_MEMORY_SCOPE_AGENT);
    lastFlag = (old == KSPLIT - 1);
  }
  __syncthreads();
  if (!lastFlag) return;
  __threadfence();  // acquire: other XCDs' partials now readable

  const float4* pp = (const float4*)part;
  const float4* b4 = (const float4*)bias;
  float4* o4 = (float4*)out;
  const int NQ = N_DIM / 4;          // 1024 float4 per row
  const int PQ = PART_ELEMS / 4;     // float4 per z-slice
  // tile = 128x128 floats = 4096 float4; 512 threads -> 8 iters
#pragma unroll
  for (int i = 0; i < 8; ++i) {
    const int fl = i * 512 + t;      // 0..4095
    const int row = fl >> 5;         // 0..127
    const int col = fl & 31;         // float4 col within tile
    const size_t base = (size_t)(m0 + row) * NQ + (n0 >> 2) + col;
    float4 s0 = pp[base];
    float4 s1 = pp[base + PQ];
    float4 s2 = pp[base + 2 * PQ];
    float4 s3 = pp[base + 3 * PQ];
    float4 bb = b4[(n0 >> 2) + col];
    float4 r;
    r.x = s0.x + s1.x + s2.x + s3.x + bb.x;
    r.y = s0.y + s1.y + s2.y + s3.y + bb.y;
    r.z = s0.z + s1.z + s2.z + s3.z + bb.z;
    r.w = s0.w + s1.w + s2.w + s3.w + bb.w;
    o4[base] = r;
  }
}

extern "C" void kernel_launch(void* const* d_in, const int* in_sizes, int n_in,
                              void* d_out, int out_size, void* d_ws,
                              size_t ws_size, hipStream_t stream) {
  const float* x = (const float*)d_in[0];     // [512, 4096]
  const float* w = (const float*)d_in[1];     // [512, 512, 8, 8]
  const float* bias = (const float*)d_in[2];  // [512, 8]
  float* out = (float*)d_out;                 // [512, 4096]

  unsigned short* abf = (unsigned short*)d_ws;       // [0, 4MB) bf16 A
  unsigned short* bt = abf + (size_t)M_DIM * K_DIM;  // [4MB, 36MB) bf16 B^T
  float* part = (float*)((char*)d_ws + 36u * 1024 * 1024);  // [36MB, 68MB)
  int* cnt = (int*)((char*)d_ws + 68u * 1024 * 1024);       // 128 ints

  const bool have_ws = ws_size >= 69ull * 1024 * 1024;
  const int use_atomic = have_ws ? 0 : 1;

  // bias-init segment only needed for the atomic fallback path
  prep_kernel<<<use_atomic ? 7168 : 5120, 256, 0, stream>>>(x, w, bias, abf,
                                                            bt, out, cnt);

  dim3 grid(N_DIM / 128, M_DIM / 128, KSPLIT);  // 32 x 4 x 4 = 512 blocks
  gemm_kernel<<<grid, 512, 0, stream>>>(abf, bt, bias, out, part, cnt,
                                        use_atomic);
}

// Round 9
// 149.075 us; speedup vs baseline: 2.0760x; 2.0760x over previous
//
#include <hip/hip_runtime.h>
#include <stdint.h>

// OctonionLinear == GEMM: out[b, i*8+k] = sum_{j,p} x[b, j*8+p] * W[i,j,p,k] + bias[i,k]
// M=512, N=4096, K=4096, fp32 in/out, bf16 MFMA.
// R9: revert R8's fused-fence epilogue (device-scope __threadfence per block
//   = per-XCD L2 writeback/invalidate x512 -> 208us gemm; kernel boundary is
//   ONE global fence and costs ~7us). Back to R7's separate reduce kernel.
//   GEMM reshaped for LDS-traffic: tile 128M x 256N, 512 thr = 8 waves of
//   64x64 (4x4 mfma16, ~92-100 VGPR unified — R1 compiled this wave shape at
//   92). Fragment-read redundancy drops (A 2x, B 2x vs R7's A 4x), LDS
//   traffic 88KB/block-iter over 2x FLOPs = 0.55x per-FLOP; L2 staging 2.6x
//   less. KSPLIT=8 keeps 512 blocks = 2 blocks/CU = 16 waves/CU.
//   Partials: 8 x 8MB slices; reduce kernel sums + bias (deterministic).

#define M_DIM 512
#define N_DIM 4096
#define K_DIM 4096
#define KSPLIT 8
#define NIT ((K_DIM / KSPLIT) / 32)  // 16
#define PART_ELEMS (M_DIM * N_DIM)   // 2097152 floats per z-slice

typedef __bf16 bf16x8 __attribute__((ext_vector_type(8)));
typedef float f32x4 __attribute__((ext_vector_type(4)));

__device__ inline unsigned short f2bf(float f) {
  union { float f; unsigned int u; } v;
  v.f = f;
  unsigned int u = v.u;
  unsigned int r = (u + 0x7fffu + ((u >> 16) & 1u)) >> 16;  // RNE
  return (unsigned short)r;
}

// blocks [0,4096): W transpose+convert -> bt[nn][kk], coalesced 16KB chunks.
// blocks [4096,5120): x convert -> abf, 8 el/thread.
// blocks [5120,7168): out = bias broadcast (ONLY in atomic fallback path).
__global__ __launch_bounds__(256) void prep_kernel(
    const float* __restrict__ x, const float* __restrict__ w,
    const float* __restrict__ bias, unsigned short* __restrict__ abf,
    unsigned short* __restrict__ bt, float* __restrict__ out) {
  const int bid = blockIdx.x;
  const int t = threadIdx.x;
  if (bid < 4096) {
    __shared__ __align__(16) unsigned short lT[8][512];  // [k][j'*8+p], 8KB
    const int i = bid >> 3;
    const int jg = bid & 7;
    const float4* src =
        (const float4*)(w + (size_t)i * 32768 + jg * 4096 + t * 16);
    float4 v0 = src[0], v1 = src[1], v2 = src[2], v3 = src[3];
    const int jp = (t >> 2) * 8 + (t & 3) * 2;  // j'*8 + p0 (even)
    const float* lo = (const float*)&v0;  // k=0..3, p0   (v1: k=4..7)
    const float* hi = (const float*)&v2;  // k=0..3, p0+1 (v3: k=4..7)
#pragma unroll
    for (int k = 0; k < 4; ++k) {
      unsigned int pk =
          (unsigned int)f2bf(lo[k]) | ((unsigned int)f2bf(hi[k]) << 16);
      *(unsigned int*)&lT[k][jp] = pk;
    }
    lo = (const float*)&v1;
    hi = (const float*)&v3;
#pragma unroll
    for (int k = 0; k < 4; ++k) {
      unsigned int pk =
          (unsigned int)f2bf(lo[k]) | ((unsigned int)f2bf(hi[k]) << 16);
      *(unsigned int*)&lT[k + 4][jp] = pk;
    }
    __syncthreads();
    const int r = t >> 5, c = t & 31;  // 32B/thread, 1KB contiguous runs
    const uint4* s = (const uint4*)&lT[r][c * 16];
    uint4* d = (uint4*)(bt + (size_t)(i * 8 + r) * K_DIM + jg * 512 + c * 16);
    d[0] = s[0];
    d[1] = s[1];
  } else if (bid < 5120) {
    int g = (bid - 4096) * 256 + t;  // [0, 262144); 8 elements each
    const float4* xi = (const float4*)x;
    float4 a = xi[g * 2];
    float4 b = xi[g * 2 + 1];
    __attribute__((aligned(16))) unsigned short o[8] = {
        f2bf(a.x), f2bf(a.y), f2bf(a.z), f2bf(a.w),
        f2bf(b.x), f2bf(b.y), f2bf(b.z), f2bf(b.w)};
    *(uint4*)(abf + (size_t)g * 8) = *(const uint4*)o;
  } else {
    int g = (bid - 5120) * 256 + t;  // [0, 524288); 4 elements each
    int el = g * 4;
    int col = el & (N_DIM - 1);
    *(float4*)(out + el) = *(const float4*)(bias + col);
  }
}

__device__ inline void gld16(const void* g, void* l) {
  __builtin_amdgcn_global_load_lds(
      (const __attribute__((address_space(1))) unsigned int*)g,
      (__attribute__((address_space(3))) unsigned int*)l, 16, 0, 0);
}

// Tile 128M x 256N, BK=32, 512 threads = 8 waves, wave-tile 64M x 64N (4x4).
// LDS/buf: A 128x32 (8KB) @0 + B 256x32 (16KB) @8KB = 24KB; dbuf = 48KB.
// 2 blocks/CU resident (16 waves/CU) via launch_bounds(512,4) -> VGPR<=128.
__global__ __launch_bounds__(512, 4) void gemm_kernel(
    const unsigned short* __restrict__ A, const unsigned short* __restrict__ Bt,
    float* __restrict__ out, float* __restrict__ part, int use_atomic) {
  __shared__ __align__(16) char lds[2][24 * 1024];
  const int t = threadIdx.x;
  const int n0 = blockIdx.x * 256;
  const int m0 = blockIdx.y * 128;
  const int z = blockIdx.z;
  const int kc0 = z * (K_DIM / KSPLIT);
  const int w = t >> 6;
  const int lane = t & 63;
  const int wr = w >> 2;     // 0..1 -> 64 M-rows
  const int wc = w & 3;      // 0..3 -> 64 N-cols
  const int lrow = lane & 15;
  const int kb = lane >> 4;  // k-block 0..3 (8 bf16 each)

  f32x4 acc[4][4] = {};

  // staging per iter: A 512 segs (seg t), B 1024 segs (segs t, t+512);
  // seg s: row s>>2, col (s&3)*8. LDS dest = wave-uniform base + lane*16.
  const size_t aOff = (size_t)(m0 + (t >> 2)) * K_DIM + kc0 + (t & 3) * 8;
  const size_t bOff0 = (size_t)(n0 + (t >> 2)) * K_DIM + kc0 + (t & 3) * 8;
  const size_t bOff1 = bOff0 + (size_t)128 * K_DIM;  // rows 128..255

  auto issue = [&](int it) {
    char* buf = lds[it & 1];
    gld16(A + aOff + it * 32, buf + t * 16);
    gld16(Bt + bOff0 + it * 32, buf + 8192 + t * 16);
    gld16(Bt + bOff1 + it * 32, buf + 16384 + t * 16);
  };

  issue(0);
  for (int it = 0; it < NIT; ++it) {
    __syncthreads();
    if (it + 1 < NIT) issue(it + 1);
    const unsigned short* cA = (const unsigned short*)lds[it & 1];
    const unsigned short* cB = cA + 4096;  // +8KB

    bf16x8 af[4], bfr[4];
#pragma unroll
    for (int mt = 0; mt < 4; ++mt)
      af[mt] = *(const bf16x8*)(cA + (wr * 64 + mt * 16 + lrow) * 32 + kb * 8);
#pragma unroll
    for (int nt = 0; nt < 4; ++nt)
      bfr[nt] = *(const bf16x8*)(cB + (wc * 64 + nt * 16 + lrow) * 32 + kb * 8);
#pragma unroll
    for (int mt = 0; mt < 4; ++mt)
#pragma unroll
      for (int nt = 0; nt < 4; ++nt)
        acc[mt][nt] = __builtin_amdgcn_mfma_f32_16x16x32_bf16(
            af[mt], bfr[nt], acc[mt][nt], 0, 0, 0);
  }

  // C/D layout (verified m89/m91): col = lane&15, row = (lane>>4)*4 + reg
#pragma unroll
  for (int mt = 0; mt < 4; ++mt) {
    const int gmb = m0 + wr * 64 + mt * 16 + kb * 4;
#pragma unroll
    for (int nt = 0; nt < 4; ++nt) {
      const int gn = n0 + wc * 64 + nt * 16 + lrow;
      if (use_atomic) {
#pragma unroll
        for (int r = 0; r < 4; ++r)
          atomicAdd(out + (size_t)(gmb + r) * N_DIM + gn, acc[mt][nt][r]);
      } else {
        float* p = part + (size_t)z * PART_ELEMS;
#pragma unroll
        for (int r = 0; r < 4; ++r)
          p[(size_t)(gmb + r) * N_DIM + gn] = acc[mt][nt][r];
      }
    }
  }
}

// out = bias + sum_z part[z] ; 2048 blocks x 256 thr x 1 float4 each
__global__ __launch_bounds__(256) void reduce_kernel(
    const float* __restrict__ part, const float* __restrict__ bias,
    float* __restrict__ out) {
  const int g = blockIdx.x * 256 + threadIdx.x;  // [0, 524288)
  const float4* p = (const float4*)part;
  const int Q = PART_ELEMS / 4;
  float4 r = ((const float4*)bias)[g & (N_DIM / 4 - 1)];
#pragma unroll
  for (int z = 0; z < KSPLIT; ++z) {
    float4 s = p[(size_t)g + (size_t)z * Q];
    r.x += s.x;
    r.y += s.y;
    r.z += s.z;
    r.w += s.w;
  }
  ((float4*)out)[g] = r;
}

extern "C" void kernel_launch(void* const* d_in, const int* in_sizes, int n_in,
                              void* d_out, int out_size, void* d_ws,
                              size_t ws_size, hipStream_t stream) {
  const float* x = (const float*)d_in[0];     // [512, 4096]
  const float* w = (const float*)d_in[1];     // [512, 512, 8, 8]
  const float* bias = (const float*)d_in[2];  // [512, 8]
  float* out = (float*)d_out;                 // [512, 4096]

  unsigned short* abf = (unsigned short*)d_ws;       // [0, 4MB) bf16 A
  unsigned short* bt = abf + (size_t)M_DIM * K_DIM;  // [4MB, 36MB) bf16 B^T
  float* part = (float*)((char*)d_ws + 36u * 1024 * 1024);  // [36MB, 100MB)

  const bool have_ws = ws_size >= 101ull * 1024 * 1024;
  const int use_atomic = have_ws ? 0 : 1;

  // bias-init segment only needed for the atomic fallback path
  prep_kernel<<<use_atomic ? 7168 : 5120, 256, 0, stream>>>(x, w, bias, abf,
                                                            bt, out);

  dim3 grid(N_DIM / 256, M_DIM / 128, KSPLIT);  // 16 x 4 x 8 = 512 blocks
  gemm_kernel<<<grid, 512, 0, stream>>>(abf, bt, out, part, use_atomic);

  if (!use_atomic)
    reduce_kernel<<<PART_ELEMS / 4 / 256, 256, 0, stream>>>(part, bias, out);
}

// Round 10
// 142.870 us; speedup vs baseline: 2.1662x; 1.0434x over previous
//
#include <hip/hip_runtime.h>
#include <stdint.h>

// OctonionLinear == GEMM: out[b, i*8+k] = sum_{j,p} x[b, j*8+p] * W[i,j,p,k] + bias[i,k]
// M=512, N=4096, K=4096, fp32 in/out, bf16 MFMA.
// R10: fuse the W->B transform INTO the GEMM. R9 accounting: resets ~65
//   (fixed) + prep ~35 + gemm ~32 + reduce ~7..11. Bt materialization was
//   pure overhead (64MB read + 32MB write + 33MB refetch). Now: tile =
//   full-M 512 x 64N, grid 64x1x4 (KSPLIT=4) = 256 blocks = 1/CU, 8 waves
//   of 64Mx64N (4x4 mfma16). Per iter threads t<256 read 8 strided W floats
//   (one (i,j,k) column), convert to bf16x8, ds_write_b128 into the B-tile:
//   W is read from HBM exactly once and Bt never exists. A (bf16 from a
//   ~3us x-convert prep) stages via global_load_lds. W loads for it+1 issue
//   at iter top, ds_write after the MFMA block -> latency hidden.
//   LDS 2 x (A 32KB + B 4KB) = 72KB, launch_bounds(512,2).
//   R8 lesson kept: no device-scope fences in-kernel; separate reduce.

#define M_DIM 512
#define N_DIM 4096
#define K_DIM 4096
#define KSPLIT 4
#define KC (K_DIM / KSPLIT)          // 1024
#define NIT (KC / 32)                // 32
#define PART_ELEMS (M_DIM * N_DIM)   // 2097152 floats per z-slice

typedef __bf16 bf16x8 __attribute__((ext_vector_type(8)));
typedef float f32x4 __attribute__((ext_vector_type(4)));

__device__ inline unsigned short f2bf(float f) {
  union { float f; unsigned int u; } v;
  v.f = f;
  unsigned int u = v.u;
  unsigned int r = (u + 0x7fffu + ((u >> 16) & 1u)) >> 16;  // RNE
  return (unsigned short)r;
}

// blocks [0,1024): x convert -> abf bf16, 8 el/thread.
// blocks [1024,3072): out = bias broadcast (ONLY in atomic fallback path).
__global__ __launch_bounds__(256) void prep_kernel(
    const float* __restrict__ x, const float* __restrict__ bias,
    unsigned short* __restrict__ abf, float* __restrict__ out) {
  const int bid = blockIdx.x;
  const int t = threadIdx.x;
  if (bid < 1024) {
    int g = bid * 256 + t;  // [0, 262144); 8 elements each
    const float4* xi = (const float4*)x;
    float4 a = xi[g * 2];
    float4 b = xi[g * 2 + 1];
    __attribute__((aligned(16))) unsigned short o[8] = {
        f2bf(a.x), f2bf(a.y), f2bf(a.z), f2bf(a.w),
        f2bf(b.x), f2bf(b.y), f2bf(b.z), f2bf(b.w)};
    *(uint4*)(abf + (size_t)g * 8) = *(const uint4*)o;
  } else {
    int g = (bid - 1024) * 256 + t;  // [0, 524288); 4 elements each
    int el = g * 4;
    int col = el & (N_DIM - 1);
    *(float4*)(out + el) = *(const float4*)(bias + col);
  }
}

__device__ inline void gld16(const void* g, void* l) {
  __builtin_amdgcn_global_load_lds(
      (const __attribute__((address_space(1))) unsigned int*)g,
      (__attribute__((address_space(3))) unsigned int*)l, 16, 0, 0);
}

// Tile 512M x 64N, BK=32. 512 thr = 8 waves; wave w owns M rows [w*64,w*64+64),
// all 64 N cols (4x4 mfma16). LDS buffer: A 512x32bf16 (32KB) @0 + B 64x32
// (4KB) @32KB; dbuf = 72KB. Grid 64 x 1 x KSPLIT = 256 blocks = 1/CU.
__global__ __launch_bounds__(512, 2) void gemm_kernel(
    const unsigned short* __restrict__ A, const float* __restrict__ W,
    float* __restrict__ out, float* __restrict__ part, int use_atomic) {
  __shared__ __align__(16) char lds[2][36 * 1024];
  const int t = threadIdx.x;
  const int bn = blockIdx.x;  // 0..63
  const int n0 = bn * 64;
  const int z = blockIdx.z;
  const int kc0 = z * KC;
  const int w = t >> 6;
  const int lane = t & 63;
  const int lrow = lane & 15;
  const int kb = lane >> 4;  // k-block 0..3 (8 bf16 each)

  f32x4 acc[4][4] = {};

  // ---- A staging: 2048 x 16B segs/iter, 4 per thread (q-planes of 8KB).
  // seg = t + q*512: row = seg>>2, col8 = (seg&3)*8; LDS byte = t*16 + q*8192
  // (= wave-uniform base (w*1024+q*8192) + lane*16, HW-compatible).
  auto issueA = [&](int it) {
    char* buf = lds[it & 1];
#pragma unroll
    for (int q = 0; q < 4; ++q) {
      const int seg = t + q * 512;
      gld16(A + (size_t)(seg >> 2) * K_DIM + kc0 + it * 32 + (seg & 3) * 8,
            buf + t * 16 + q * 8192);
    }
  };

  // ---- W staging (threads t<256): thread = (wi, jl, wk) reads the 8-float
  // p-column of W[i0+wi][j0+jl][*][wk], converts, writes one bf16x8 B-row
  // segment [n=wi*8+wk][jl*8 .. +8]. j0 = z*128 + it*4.
  const int wi = t >> 5;          // 0..7
  const int jl = (t >> 3) & 3;    // 0..3
  const int wk = t & 7;           // 0..7
  const float* wcol =
      W + ((size_t)(bn * 8 + wi) * 512 + (size_t)(z * 128) + jl) * 64 + wk;

  float wcur[8], wnxt[8];
  auto loadW = [&](int it, float* r) {
    if (t < 256) {
      const float* p = wcol + (size_t)it * 4 * 64;
#pragma unroll
      for (int pp = 0; pp < 8; ++pp) r[pp] = p[pp * 8];
    }
  };
  auto writeW = [&](int it, const float* r) {
    if (t < 256) {
      __attribute__((aligned(16))) unsigned short o[8];
#pragma unroll
      for (int pp = 0; pp < 8; ++pp) o[pp] = f2bf(r[pp]);
      *(uint4*)(lds[it & 1] + 32768 + (wi * 8 + wk) * 64 + jl * 16) =
          *(const uint4*)o;
    }
  };

  issueA(0);
  loadW(0, wcur);
  writeW(0, wcur);

  for (int it = 0; it < NIT; ++it) {
    __syncthreads();  // buf[it&1] fully staged (A-DMA vmcnt + W lgkm drain)
    if (it + 1 < NIT) {
      issueA(it + 1);
      loadW(it + 1, wnxt);
    }
    const unsigned short* cA = (const unsigned short*)lds[it & 1];
    const unsigned short* cB = (const unsigned short*)(lds[it & 1] + 32768);

    bf16x8 af[4], bfr[4];
#pragma unroll
    for (int mt = 0; mt < 4; ++mt)
      af[mt] = *(const bf16x8*)(cA + (w * 64 + mt * 16 + lrow) * 32 + kb * 8);
#pragma unroll
    for (int nt = 0; nt < 4; ++nt)
      bfr[nt] = *(const bf16x8*)(cB + (nt * 16 + lrow) * 32 + kb * 8);
#pragma unroll
    for (int mt = 0; mt < 4; ++mt)
#pragma unroll
      for (int nt = 0; nt < 4; ++nt)
        acc[mt][nt] = __builtin_amdgcn_mfma_f32_16x16x32_bf16(
            af[mt], bfr[nt], acc[mt][nt], 0, 0, 0);

    if (it + 1 < NIT) writeW(it + 1, wnxt);  // W loads had full MFMA phase
  }

  // C/D layout (verified m89/m91): col = lane&15, row = (lane>>4)*4 + reg
#pragma unroll
  for (int mt = 0; mt < 4; ++mt) {
    const int gmb = w * 64 + mt * 16 + kb * 4;
#pragma unroll
    for (int nt = 0; nt < 4; ++nt) {
      const int gn = n0 + nt * 16 + lrow;
      if (use_atomic) {
#pragma unroll
        for (int r = 0; r < 4; ++r)
          atomicAdd(out + (size_t)(gmb + r) * N_DIM + gn, acc[mt][nt][r]);
      } else {
        float* p = part + (size_t)z * PART_ELEMS;
#pragma unroll
        for (int r = 0; r < 4; ++r)
          p[(size_t)(gmb + r) * N_DIM + gn] = acc[mt][nt][r];
      }
    }
  }
}

// out = bias + sum_z part[z] ; 2048 blocks x 256 thr x 1 float4 each
__global__ __launch_bounds__(256) void reduce_kernel(
    const float* __restrict__ part, const float* __restrict__ bias,
    float* __restrict__ out) {
  const int g = blockIdx.x * 256 + threadIdx.x;  // [0, 524288)
  const float4* p = (const float4*)part;
  const int Q = PART_ELEMS / 4;
  float4 r = ((const float4*)bias)[g & (N_DIM / 4 - 1)];
#pragma unroll
  for (int z = 0; z < KSPLIT; ++z) {
    float4 s = p[(size_t)g + (size_t)z * Q];
    r.x += s.x;
    r.y += s.y;
    r.z += s.z;
    r.w += s.w;
  }
  ((float4*)out)[g] = r;
}

extern "C" void kernel_launch(void* const* d_in, const int* in_sizes, int n_in,
                              void* d_out, int out_size, void* d_ws,
                              size_t ws_size, hipStream_t stream) {
  const float* x = (const float*)d_in[0];     // [512, 4096]
  const float* w = (const float*)d_in[1];     // [512, 512, 8, 8]
  const float* bias = (const float*)d_in[2];  // [512, 8]
  float* out = (float*)d_out;                 // [512, 4096]

  unsigned short* abf = (unsigned short*)d_ws;              // [0, 4MB) bf16 A
  float* part = (float*)((char*)d_ws + 4u * 1024 * 1024);   // [4MB, 36MB)

  const bool have_ws = ws_size >= 37ull * 1024 * 1024;
  const int use_atomic = have_ws ? 0 : 1;

  // bias-init segment only needed for the atomic fallback path
  prep_kernel<<<use_atomic ? 3072 : 1024, 256, 0, stream>>>(x, bias, abf, out);

  dim3 grid(N_DIM / 64, 1, KSPLIT);  // 64 x 1 x 4 = 256 blocks (1/CU)
  gemm_kernel<<<grid, 512, 0, stream>>>(abf, w, out, part, use_atomic);

  if (!use_atomic)
    reduce_kernel<<<PART_ELEMS / 4 / 256, 256, 0, stream>>>(part, bias, out);
}